// Round 2
// baseline (381.983 us; speedup 1.0000x reference)
//
#include <hip/hip_runtime.h>

// Problem: B=8, H=W=128, C=192, NH=6, hd=32, window 8x8 (64 tok), 2048 windows.
// FP32 I/O; bf16 MFMA internally (threshold ~2% rel).
//
// Round 2: fused QKV+attn made barrier-free (per-wave x loads from global,
// round-0 pattern) and per-wave LDS shrunk to 12 KB via stride-64 XOR-swizzled
// buffers -> 2 blocks/CU (12 waves/CU) instead of 1 (6 waves/CU).

typedef __attribute__((ext_vector_type(8))) short bf16x8;
typedef __attribute__((ext_vector_type(4))) float f32x4;

__device__ __forceinline__ float bf2f(unsigned short h) {
    return __builtin_bit_cast(float, (unsigned int)h << 16);
}
__device__ __forceinline__ unsigned short f2bf(float f) {
    unsigned int u = __builtin_bit_cast(unsigned int, f);
    u += 0x7fffu + ((u >> 16) & 1u);
    return (unsigned short)(u >> 16);
}
__device__ __forceinline__ bf16x8 ld8(const unsigned short* p) {
    return *(const bf16x8*)p;
}
__device__ __forceinline__ bf16x8 ldf8(const float* p) {
    float4 a = *(const float4*)p;
    float4 b = *(const float4*)(p + 4);
    bf16x8 r;
    r[0] = (short)f2bf(a.x); r[1] = (short)f2bf(a.y);
    r[2] = (short)f2bf(a.z); r[3] = (short)f2bf(a.w);
    r[4] = (short)f2bf(b.x); r[5] = (short)f2bf(b.y);
    r[6] = (short)f2bf(b.z); r[7] = (short)f2bf(b.w);
    return r;
}

// ---------------------------------------------------------------------------
// K0: repack w_qkv/w_proj (fp32) into bf16 MFMA B-fragment order. (unchanged)
// ---------------------------------------------------------------------------
__global__ __launch_bounds__(256) void repack_kernel(
    const float* __restrict__ w_qkv, const float* __restrict__ w_proj,
    unsigned short* __restrict__ wq_m, unsigned short* __restrict__ wp_m)
{
    int f = blockIdx.x * 256 + threadIdx.x;
    if (f < 6 * 36 * 64 * 8) {
        int j = f & 7, lane = (f >> 3) & 63, rest = f >> 9;
        int nt = rest % 36, kt = rest / 36;
        wq_m[f] = f2bf(w_qkv[(kt * 32 + (lane >> 4) * 8 + j) * 576 + nt * 16 + (lane & 15)]);
    }
    if (f < 6 * 12 * 64 * 8) {
        int j = f & 7, lane = (f >> 3) & 63, rest = f >> 9;
        int nt = rest % 12, kt = rest / 12;
        wp_m[f] = f2bf(w_proj[(kt * 32 + (lane >> 4) * 8 + j) * 192 + nt * 16 + (lane & 15)]);
    }
}

// ---------------------------------------------------------------------------
// K_F: fused QKV + attention. 1 window per block, 6 waves, wave h == head h.
// Barrier-free: each wave loads x A-fragments straight from global (L1/L2
// shared across the 6 waves) and owns a private 6144-u16 LDS region.
//
// Per-wave LDS (u16 units), all stride-64 rows (128 B), XOR-swizzled
// col' = col ^ ((row & 7) << 3)  (keeps 16B alignment of 8-u16 chunks):
//   qk  +0     [64 rows][64]  logical cols 0..31 = q (scaled), 32..63 = k
//   Ps  +0     [64 rows][64]  ALIASES qk — written only after aq/bk consumed
//                             (same-wave DS ops in-order; proven round 1)
//   vT  +4096  [32 rows][64]  v transposed, B-operand layout
// Block total: 6 * 6144 u16 = 73728 B -> 2 blocks/CU.
//
// Frag conventions (same as prior verified kernels):
//   a[j]=A[l16][quad*8+j]; b[j]=B[quad*8+j][l16]; d[r]=D[quad*4+r][l16].
// ---------------------------------------------------------------------------
__global__ __launch_bounds__(384, 3) void qkv_attn_fused(
    const float* __restrict__ x, const unsigned short* __restrict__ wq_m,
    const float* __restrict__ b_qkv, unsigned short* __restrict__ o_scr)
{
    __shared__ unsigned short smem[6 * 6144];

    const int tid = threadIdx.x, lane = tid & 63, h = tid >> 6;
    const int l16 = lane & 15, quad = lane >> 4;
    const int wi = blockIdx.x;
    const int img = wi >> 8, wrem = wi & 255;
    const int y0 = (wrem >> 4) * 8, x0 = (wrem & 15) * 8;

    unsigned short* qk = smem + h * 6144;   // + Ps alias
    unsigned short* vT = qk + 4096;

    // ---- per-wave x row pointers (round-0 qkv_gemm pattern) ----
    const float* xrow[4];
#pragma unroll
    for (int mt = 0; mt < 4; ++mt) {
        int token = mt * 16 + l16;
        xrow[mt] = x + ((img * 128 + y0 + (token >> 3)) * 128 + (x0 + (token & 7))) * 192;
    }

    // ---- phase 1: QKV GEMM, the 6 N-tiles this head needs ----
    // tiles: q = {2h, 2h+1}, k = {12+2h, 13+2h}, v = {24+2h, 25+2h}
    const int ntb[6] = {2 * h, 2 * h + 1, 12 + 2 * h, 13 + 2 * h, 24 + 2 * h, 25 + 2 * h};

    f32x4 acc[6][4];
#pragma unroll
    for (int s = 0; s < 6; ++s)
#pragma unroll
        for (int mt = 0; mt < 4; ++mt) acc[s][mt] = (f32x4){0.f, 0.f, 0.f, 0.f};

    for (int kt = 0; kt < 6; ++kt) {
        bf16x8 af[4];
#pragma unroll
        for (int mt = 0; mt < 4; ++mt) af[mt] = ldf8(xrow[mt] + kt * 32 + quad * 8);
#pragma unroll
        for (int s = 0; s < 6; ++s) {
            bf16x8 bw = ld8(wq_m + (((kt * 36 + ntb[s]) * 64 + lane) << 3));
#pragma unroll
            for (int mt = 0; mt < 4; ++mt)
                acc[s][mt] = __builtin_amdgcn_mfma_f32_16x16x32_bf16(af[mt], bw, acc[s][mt], 0, 0, 0);
        }
    }

    // ---- phase 2: scatter q (scaled), k, vT into this wave's LDS ----
#pragma unroll
    for (int s = 0; s < 6; ++s) {
        const float bias = b_qkv[ntb[s] * 16 + l16];
        if (s < 4) {                       // q (s<2) or k (s<4): col = s*16+l16
            const int c0 = s * 16 + l16;
            const float scl = (s < 2) ? 0.17677669529663687f : 1.0f;
#pragma unroll
            for (int mt = 0; mt < 4; ++mt)
#pragma unroll
                for (int r = 0; r < 4; ++r) {
                    const int row = mt * 16 + quad * 4 + r;
                    qk[row * 64 + (c0 ^ ((row & 7) << 3))] =
                        f2bf((acc[s][mt][r] + bias) * scl);
                }
        } else {                           // v -> vT[dim][tok]
            const int rowv = (s - 4) * 16 + l16;
            const int sw = (rowv & 7) << 3;
#pragma unroll
            for (int mt = 0; mt < 4; ++mt)
#pragma unroll
                for (int r = 0; r < 4; ++r) {
                    const int tok = mt * 16 + quad * 4 + r;
                    vT[rowv * 64 + (tok ^ sw)] = f2bf(acc[s][mt][r] + bias);
                }
        }
    }

    // ---- phase 3: S = q k^T (no barrier: same-wave LDS round-trip) ----
    bf16x8 aq[4], bk[4];
#pragma unroll
    for (int mt = 0; mt < 4; ++mt) {
        const int row = mt * 16 + l16;
        aq[mt] = ld8(qk + row * 64 + ((quad * 8) ^ ((row & 7) << 3)));
    }
#pragma unroll
    for (int nt = 0; nt < 4; ++nt) {
        const int row = nt * 16 + l16;
        bk[nt] = ld8(qk + row * 64 + ((32 + quad * 8) ^ ((row & 7) << 3)));
    }

    f32x4 s4[4][4];
#pragma unroll
    for (int mt = 0; mt < 4; ++mt)
#pragma unroll
        for (int nt = 0; nt < 4; ++nt) {
            s4[mt][nt] = (f32x4){0.f, 0.f, 0.f, 0.f};
            s4[mt][nt] = __builtin_amdgcn_mfma_f32_16x16x32_bf16(aq[mt], bk[nt], s4[mt][nt], 0, 0, 0);
        }

    // ---- phase 4: softmax per row, write normalized P (aliases dead q/k) ----
#pragma unroll
    for (int mt = 0; mt < 4; ++mt) {
#pragma unroll
        for (int r = 0; r < 4; ++r) {
            float m = fmaxf(fmaxf(s4[mt][0][r], s4[mt][1][r]), fmaxf(s4[mt][2][r], s4[mt][3][r]));
            m = fmaxf(m, __shfl_xor(m, 1, 64));
            m = fmaxf(m, __shfl_xor(m, 2, 64));
            m = fmaxf(m, __shfl_xor(m, 4, 64));
            m = fmaxf(m, __shfl_xor(m, 8, 64));
            float pv[4], sum = 0.f;
#pragma unroll
            for (int nt = 0; nt < 4; ++nt) { pv[nt] = __expf(s4[mt][nt][r] - m); sum += pv[nt]; }
            sum += __shfl_xor(sum, 1, 64);
            sum += __shfl_xor(sum, 2, 64);
            sum += __shfl_xor(sum, 4, 64);
            sum += __shfl_xor(sum, 8, 64);
            const float inv = 1.f / sum;
            const int row = mt * 16 + quad * 4 + r;
            const int sw = (row & 7) << 3;
#pragma unroll
            for (int nt = 0; nt < 4; ++nt)
                qk[row * 64 + ((nt * 16 + l16) ^ sw)] = f2bf(pv[nt] * inv);
        }
    }

    // ---- phase 5: O = P V ----
    f32x4 o[4][2];
#pragma unroll
    for (int mt = 0; mt < 4; ++mt)
#pragma unroll
        for (int n2 = 0; n2 < 2; ++n2) o[mt][n2] = (f32x4){0.f, 0.f, 0.f, 0.f};

#pragma unroll
    for (int kt2 = 0; kt2 < 2; ++kt2) {
        bf16x8 bv[2];
#pragma unroll
        for (int n2 = 0; n2 < 2; ++n2) {
            const int row = n2 * 16 + l16;
            bv[n2] = ld8(vT + row * 64 + ((kt2 * 32 + quad * 8) ^ ((row & 7) << 3)));
        }
#pragma unroll
        for (int mt = 0; mt < 4; ++mt) {
            const int row = mt * 16 + l16;
            bf16x8 ap = ld8(qk + row * 64 + ((kt2 * 32 + quad * 8) ^ ((row & 7) << 3)));
#pragma unroll
            for (int n2 = 0; n2 < 2; ++n2)
                o[mt][n2] = __builtin_amdgcn_mfma_f32_16x16x32_bf16(ap, bv[n2], o[mt][n2], 0, 0, 0);
        }
    }

#pragma unroll
    for (int mt = 0; mt < 4; ++mt)
#pragma unroll
        for (int n2 = 0; n2 < 2; ++n2)
#pragma unroll
            for (int r = 0; r < 4; ++r) {
                const int token = mt * 16 + quad * 4 + r;
                o_scr[((img * 128 + y0 + (token >> 3)) * 128 + (x0 + (token & 7))) * 192
                      + h * 32 + n2 * 16 + l16] = f2bf(o[mt][n2][r]);
            }
}

// ---------------------------------------------------------------------------
// K_C: depthwise 3x3 (vectorized 8-ch) + proj GEMM. (unchanged)
// ---------------------------------------------------------------------------
__global__ __launch_bounds__(256, 2) void conv_proj_kernel(
    const unsigned short* __restrict__ o_scr,
    const float* __restrict__ w_dw, const float* __restrict__ b_dw,
    const unsigned short* __restrict__ wp_m, const float* __restrict__ b_proj,
    float* __restrict__ out)
{
    __shared__ unsigned short oh[100 * 192];
    __shared__ unsigned short cb[64 * 200];
    __shared__ float wdw_s[9 * 192];
    __shared__ float bdw_s[192];

    const int tid = threadIdx.x, lane = tid & 63, wave = tid >> 6;
    const int l16 = lane & 15, quad = lane >> 4;
    const int img = blockIdx.x >> 8, wrem = blockIdx.x & 255;
    const int y0 = (wrem >> 4) * 8, x0 = (wrem & 15) * 8;

    for (int i = tid; i < 9 * 192; i += 256) wdw_s[i] = w_dw[i];
    if (tid < 192) bdw_s[tid] = b_dw[tid];

    for (int c = tid; c < 2400; c += 256) {
        int pix = c / 24, ck = c % 24;
        int py = y0 - 1 + pix / 10, px = x0 - 1 + pix % 10;
        uint4 v = {0u, 0u, 0u, 0u};
        if (py >= 0 && py < 128 && px >= 0 && px < 128)
            v = *(const uint4*)(o_scr + ((img * 128 + py) * 128 + px) * 192 + ck * 8);
        *(uint4*)(oh + pix * 192 + ck * 8) = v;
    }
    __syncthreads();

    // conv: item = (token, 8-channel chunk); 6 items/thread
#pragma unroll
    for (int k = 0; k < 6; ++k) {
        int idx = k * 256 + tid;
        int c8 = idx % 24, t = idx / 24;
        int r = t >> 3, cc = t & 7;
        float a[8];
#pragma unroll
        for (int i = 0; i < 8; ++i) a[i] = bdw_s[c8 * 8 + i];
#pragma unroll
        for (int dy = 0; dy < 3; ++dy)
#pragma unroll
            for (int dx = 0; dx < 3; ++dx) {
                bf16x8 hv = ld8(&oh[((r + dy) * 10 + (cc + dx)) * 192 + c8 * 8]);
                const float* wp = &wdw_s[(dy * 3 + dx) * 192 + c8 * 8];
#pragma unroll
                for (int i = 0; i < 8; ++i)
                    a[i] += bf2f((unsigned short)hv[i]) * wp[i];
            }
        bf16x8 rv;
#pragma unroll
        for (int i = 0; i < 8; ++i) rv[i] = (short)f2bf(a[i]);
        *(bf16x8*)&cb[t * 200 + c8 * 8] = rv;
    }
    __syncthreads();

    f32x4 po[3][4];
#pragma unroll
    for (int n = 0; n < 3; ++n)
#pragma unroll
        for (int mt = 0; mt < 4; ++mt) po[n][mt] = (f32x4){0.f, 0.f, 0.f, 0.f};

    for (int kt = 0; kt < 6; ++kt) {
        bf16x8 af[4];
#pragma unroll
        for (int mt = 0; mt < 4; ++mt) af[mt] = ld8(cb + (mt * 16 + l16) * 200 + kt * 32 + quad * 8);
#pragma unroll
        for (int ntl = 0; ntl < 3; ++ntl) {
            bf16x8 bw = ld8(wp_m + (((kt * 12 + wave * 3 + ntl) * 64 + lane) << 3));
#pragma unroll
            for (int mt = 0; mt < 4; ++mt)
                po[ntl][mt] = __builtin_amdgcn_mfma_f32_16x16x32_bf16(af[mt], bw, po[ntl][mt], 0, 0, 0);
        }
    }

#pragma unroll
    for (int ntl = 0; ntl < 3; ++ntl) {
        int col = (wave * 3 + ntl) * 16 + l16;
        float bias = b_proj[col];
#pragma unroll
        for (int mt = 0; mt < 4; ++mt)
#pragma unroll
            for (int r = 0; r < 4; ++r) {
                int t = mt * 16 + quad * 4 + r;
                out[((img * 128 + y0 + (t >> 3)) * 128 + (x0 + (t & 7))) * 192 + col]
                    = po[ntl][mt][r] + bias;
            }
    }
}

// ---------------------------------------------------------------------------
extern "C" void kernel_launch(void* const* d_in, const int* in_sizes, int n_in,
                              void* d_out, int out_size, void* d_ws, size_t ws_size,
                              hipStream_t stream)
{
    const float* x      = (const float*)d_in[0];
    const float* w_qkv  = (const float*)d_in[1];
    const float* b_qkv  = (const float*)d_in[2];
    const float* w_dw   = (const float*)d_in[3];
    const float* b_dw   = (const float*)d_in[4];
    const float* w_proj = (const float*)d_in[5];
    const float* b_proj = (const float*)d_in[6];
    float* out = (float*)d_out;

    // ws (u16 units): wq_m 110592 | wp_m 36864 | o_scr 25165824
    unsigned short* wq_m  = (unsigned short*)d_ws;
    unsigned short* wp_m  = wq_m + 110592;
    unsigned short* o_scr = wq_m + 147456;

    repack_kernel<<<dim3(432), dim3(256), 0, stream>>>(w_qkv, w_proj, wq_m, wp_m);
    qkv_attn_fused<<<dim3(2048), dim3(384), 0, stream>>>(x, wq_m, b_qkv, o_scr);
    conv_proj_kernel<<<dim3(2048), dim3(256), 0, stream>>>(o_scr, w_dw, b_dw, wp_m, b_proj, out);
}

// Round 3
// 317.095 us; speedup vs baseline: 1.2046x; 1.2046x over previous
//
#include <hip/hip_runtime.h>

// Problem: B=8, H=W=128, C=192, NH=6, hd=32, window 8x8 (64 tok), 2048 windows.
// FP32 I/O; bf16 MFMA internally (threshold ~2% rel).
//
// Round 3: fused QKV+attn = round-1 structure (LDS x-stage, 124 VGPR, no
// spill) + round-2 compact swizzled per-wave LDS (12 KB/wave), with the
// x-stage buffer ALIASED onto the per-wave region (x dead after phase 1;
// extra barrier makes it safe). 73728 B LDS -> 2 blocks/CU (12 waves/CU).
// Round-2 lesson: __launch_bounds__(384,3) capped VGPR at 84 -> acc[6][4]
// (96 regs) spilled to scratch (WRITE_SIZE +11.7MB). Do NOT cap registers.

typedef __attribute__((ext_vector_type(8))) short bf16x8;
typedef __attribute__((ext_vector_type(4))) float f32x4;

__device__ __forceinline__ float bf2f(unsigned short h) {
    return __builtin_bit_cast(float, (unsigned int)h << 16);
}
__device__ __forceinline__ unsigned short f2bf(float f) {
    unsigned int u = __builtin_bit_cast(unsigned int, f);
    u += 0x7fffu + ((u >> 16) & 1u);
    return (unsigned short)(u >> 16);
}
__device__ __forceinline__ bf16x8 ld8(const unsigned short* p) {
    return *(const bf16x8*)p;
}
__device__ __forceinline__ bf16x8 ldf8(const float* p) {
    float4 a = *(const float4*)p;
    float4 b = *(const float4*)(p + 4);
    bf16x8 r;
    r[0] = (short)f2bf(a.x); r[1] = (short)f2bf(a.y);
    r[2] = (short)f2bf(a.z); r[3] = (short)f2bf(a.w);
    r[4] = (short)f2bf(b.x); r[5] = (short)f2bf(b.y);
    r[6] = (short)f2bf(b.z); r[7] = (short)f2bf(b.w);
    return r;
}

// ---------------------------------------------------------------------------
// K0: repack w_qkv/w_proj (fp32) into bf16 MFMA B-fragment order. (unchanged)
// ---------------------------------------------------------------------------
__global__ __launch_bounds__(256) void repack_kernel(
    const float* __restrict__ w_qkv, const float* __restrict__ w_proj,
    unsigned short* __restrict__ wq_m, unsigned short* __restrict__ wp_m)
{
    int f = blockIdx.x * 256 + threadIdx.x;
    if (f < 6 * 36 * 64 * 8) {
        int j = f & 7, lane = (f >> 3) & 63, rest = f >> 9;
        int nt = rest % 36, kt = rest / 36;
        wq_m[f] = f2bf(w_qkv[(kt * 32 + (lane >> 4) * 8 + j) * 576 + nt * 16 + (lane & 15)]);
    }
    if (f < 6 * 12 * 64 * 8) {
        int j = f & 7, lane = (f >> 3) & 63, rest = f >> 9;
        int nt = rest % 12, kt = rest / 12;
        wp_m[f] = f2bf(w_proj[(kt * 32 + (lane >> 4) * 8 + j) * 192 + nt * 16 + (lane & 15)]);
    }
}

// ---------------------------------------------------------------------------
// K_F: fused QKV + attention. 1 window per block, 6 waves, wave h == head h.
//
// LDS: single 36864-u16 (73728 B) arena, two overlapping uses:
//   phase 0-1:  xs [tok 64][stride 200] bf16 x tile   (12800 u16, offset 0)
//   phase 2-5:  per-wave region at h*6144, stride-64 rows, XOR-swizzled
//               col' = col ^ ((row & 7) << 3):
//      qk  +0     [64][64]  cols 0..31 = q (scaled), 32..63 = k
//      Ps  +0     [64][64]  aliases qk (written after aq/bk consumed;
//                           same-wave DS ops are in-order — proven r1/r2)
//      vT  +4096  [32][64]  v transposed, B-operand layout
//   Barrier 1 after x staging; barrier 2 after GEMM (xs dead) before scatter.
//
// Frag conventions: a[j]=A[l16][quad*8+j]; b[j]=B[quad*8+j][l16];
//                   d[r]=D[quad*4+r][l16].
// ---------------------------------------------------------------------------
__global__ __launch_bounds__(384) void qkv_attn_fused(
    const float* __restrict__ x, const unsigned short* __restrict__ wq_m,
    const float* __restrict__ b_qkv, unsigned short* __restrict__ o_scr)
{
    __shared__ unsigned short smem[6 * 6144];

    const int tid = threadIdx.x, lane = tid & 63, h = tid >> 6;
    const int l16 = lane & 15, quad = lane >> 4;
    const int wi = blockIdx.x;
    const int img = wi >> 8, wrem = wi & 255;
    const int y0 = (wrem >> 4) * 8, x0 = (wrem & 15) * 8;

    unsigned short* qk = smem + h * 6144;   // + Ps alias
    unsigned short* vT = qk + 4096;

    // ---- phase 0: stage x tile fp32 -> bf16 LDS (once per block) ----
    {
        const int token = tid / 6, seg = tid % 6;   // 64 tokens x 6 segs of 32
        const float* sp = x + ((img * 128 + y0 + (token >> 3)) * 128
                               + (x0 + (token & 7))) * 192 + seg * 32;
        unsigned short* dp = smem + token * 200 + seg * 32;
#pragma unroll
        for (int i = 0; i < 4; ++i)
            *(bf16x8*)(dp + i * 8) = ldf8(sp + i * 8);
    }
    __syncthreads();

    // ---- phase 1: QKV GEMM, the 6 N-tiles this head needs ----
    // tiles: q = {2h, 2h+1}, k = {12+2h, 13+2h}, v = {24+2h, 25+2h}
    const int ntb[6] = {2 * h, 2 * h + 1, 12 + 2 * h, 13 + 2 * h, 24 + 2 * h, 25 + 2 * h};

    f32x4 acc[6][4];
#pragma unroll
    for (int s = 0; s < 6; ++s)
#pragma unroll
        for (int mt = 0; mt < 4; ++mt) acc[s][mt] = (f32x4){0.f, 0.f, 0.f, 0.f};

    for (int kt = 0; kt < 6; ++kt) {
        bf16x8 af[4];
#pragma unroll
        for (int mt = 0; mt < 4; ++mt)
            af[mt] = ld8(smem + (mt * 16 + l16) * 200 + kt * 32 + quad * 8);
#pragma unroll
        for (int s = 0; s < 6; ++s) {
            bf16x8 bw = ld8(wq_m + (((kt * 36 + ntb[s]) * 64 + lane) << 3));
#pragma unroll
            for (int mt = 0; mt < 4; ++mt)
                acc[s][mt] = __builtin_amdgcn_mfma_f32_16x16x32_bf16(af[mt], bw, acc[s][mt], 0, 0, 0);
        }
    }
    __syncthreads();   // xs dead; per-wave regions (aliasing xs) now writable

    // ---- phase 2: scatter q (scaled), k, vT into this wave's LDS ----
#pragma unroll
    for (int s = 0; s < 6; ++s) {
        const float bias = b_qkv[ntb[s] * 16 + l16];
        if (s < 4) {                       // q (s<2) or k (s<4): col = s*16+l16
            const int c0 = s * 16 + l16;
            const float scl = (s < 2) ? 0.17677669529663687f : 1.0f;
#pragma unroll
            for (int mt = 0; mt < 4; ++mt)
#pragma unroll
                for (int r = 0; r < 4; ++r) {
                    const int row = mt * 16 + quad * 4 + r;
                    qk[row * 64 + (c0 ^ ((row & 7) << 3))] =
                        f2bf((acc[s][mt][r] + bias) * scl);
                }
        } else {                           // v -> vT[dim][tok]
            const int rowv = (s - 4) * 16 + l16;
            const int sw = (rowv & 7) << 3;
#pragma unroll
            for (int mt = 0; mt < 4; ++mt)
#pragma unroll
                for (int r = 0; r < 4; ++r) {
                    const int tok = mt * 16 + quad * 4 + r;
                    vT[rowv * 64 + (tok ^ sw)] = f2bf(acc[s][mt][r] + bias);
                }
        }
    }

    // ---- phase 3: S = q k^T (no barrier: same-wave LDS round-trip) ----
    bf16x8 aq[4], bk[4];
#pragma unroll
    for (int mt = 0; mt < 4; ++mt) {
        const int row = mt * 16 + l16;
        aq[mt] = ld8(qk + row * 64 + ((quad * 8) ^ ((row & 7) << 3)));
    }
#pragma unroll
    for (int nt = 0; nt < 4; ++nt) {
        const int row = nt * 16 + l16;
        bk[nt] = ld8(qk + row * 64 + ((32 + quad * 8) ^ ((row & 7) << 3)));
    }

    f32x4 s4[4][4];
#pragma unroll
    for (int mt = 0; mt < 4; ++mt)
#pragma unroll
        for (int nt = 0; nt < 4; ++nt) {
            s4[mt][nt] = (f32x4){0.f, 0.f, 0.f, 0.f};
            s4[mt][nt] = __builtin_amdgcn_mfma_f32_16x16x32_bf16(aq[mt], bk[nt], s4[mt][nt], 0, 0, 0);
        }

    // ---- phase 4: softmax per row, write normalized P (aliases dead q/k) ----
#pragma unroll
    for (int mt = 0; mt < 4; ++mt) {
#pragma unroll
        for (int r = 0; r < 4; ++r) {
            float m = fmaxf(fmaxf(s4[mt][0][r], s4[mt][1][r]), fmaxf(s4[mt][2][r], s4[mt][3][r]));
            m = fmaxf(m, __shfl_xor(m, 1, 64));
            m = fmaxf(m, __shfl_xor(m, 2, 64));
            m = fmaxf(m, __shfl_xor(m, 4, 64));
            m = fmaxf(m, __shfl_xor(m, 8, 64));
            float pv[4], sum = 0.f;
#pragma unroll
            for (int nt = 0; nt < 4; ++nt) { pv[nt] = __expf(s4[mt][nt][r] - m); sum += pv[nt]; }
            sum += __shfl_xor(sum, 1, 64);
            sum += __shfl_xor(sum, 2, 64);
            sum += __shfl_xor(sum, 4, 64);
            sum += __shfl_xor(sum, 8, 64);
            const float inv = 1.f / sum;
            const int row = mt * 16 + quad * 4 + r;
            const int sw = (row & 7) << 3;
#pragma unroll
            for (int nt = 0; nt < 4; ++nt)
                qk[row * 64 + ((nt * 16 + l16) ^ sw)] = f2bf(pv[nt] * inv);
        }
    }

    // ---- phase 5: O = P V ----
    f32x4 o[4][2];
#pragma unroll
    for (int mt = 0; mt < 4; ++mt)
#pragma unroll
        for (int n2 = 0; n2 < 2; ++n2) o[mt][n2] = (f32x4){0.f, 0.f, 0.f, 0.f};

#pragma unroll
    for (int kt2 = 0; kt2 < 2; ++kt2) {
        bf16x8 bv[2];
#pragma unroll
        for (int n2 = 0; n2 < 2; ++n2) {
            const int row = n2 * 16 + l16;
            bv[n2] = ld8(vT + row * 64 + ((kt2 * 32 + quad * 8) ^ ((row & 7) << 3)));
        }
#pragma unroll
        for (int mt = 0; mt < 4; ++mt) {
            const int row = mt * 16 + l16;
            bf16x8 ap = ld8(qk + row * 64 + ((kt2 * 32 + quad * 8) ^ ((row & 7) << 3)));
#pragma unroll
            for (int n2 = 0; n2 < 2; ++n2)
                o[mt][n2] = __builtin_amdgcn_mfma_f32_16x16x32_bf16(ap, bv[n2], o[mt][n2], 0, 0, 0);
        }
    }

#pragma unroll
    for (int mt = 0; mt < 4; ++mt)
#pragma unroll
        for (int n2 = 0; n2 < 2; ++n2)
#pragma unroll
            for (int r = 0; r < 4; ++r) {
                const int token = mt * 16 + quad * 4 + r;
                o_scr[((img * 128 + y0 + (token >> 3)) * 128 + (x0 + (token & 7))) * 192
                      + h * 32 + n2 * 16 + l16] = f2bf(o[mt][n2][r]);
            }
}

// ---------------------------------------------------------------------------
// K_C: depthwise 3x3 (vectorized 8-ch) + proj GEMM. (unchanged)
// ---------------------------------------------------------------------------
__global__ __launch_bounds__(256, 2) void conv_proj_kernel(
    const unsigned short* __restrict__ o_scr,
    const float* __restrict__ w_dw, const float* __restrict__ b_dw,
    const unsigned short* __restrict__ wp_m, const float* __restrict__ b_proj,
    float* __restrict__ out)
{
    __shared__ unsigned short oh[100 * 192];
    __shared__ unsigned short cb[64 * 200];
    __shared__ float wdw_s[9 * 192];
    __shared__ float bdw_s[192];

    const int tid = threadIdx.x, lane = tid & 63, wave = tid >> 6;
    const int l16 = lane & 15, quad = lane >> 4;
    const int img = blockIdx.x >> 8, wrem = blockIdx.x & 255;
    const int y0 = (wrem >> 4) * 8, x0 = (wrem & 15) * 8;

    for (int i = tid; i < 9 * 192; i += 256) wdw_s[i] = w_dw[i];
    if (tid < 192) bdw_s[tid] = b_dw[tid];

    for (int c = tid; c < 2400; c += 256) {
        int pix = c / 24, ck = c % 24;
        int py = y0 - 1 + pix / 10, px = x0 - 1 + pix % 10;
        uint4 v = {0u, 0u, 0u, 0u};
        if (py >= 0 && py < 128 && px >= 0 && px < 128)
            v = *(const uint4*)(o_scr + ((img * 128 + py) * 128 + px) * 192 + ck * 8);
        *(uint4*)(oh + pix * 192 + ck * 8) = v;
    }
    __syncthreads();

    // conv: item = (token, 8-channel chunk); 6 items/thread
#pragma unroll
    for (int k = 0; k < 6; ++k) {
        int idx = k * 256 + tid;
        int c8 = idx % 24, t = idx / 24;
        int r = t >> 3, cc = t & 7;
        float a[8];
#pragma unroll
        for (int i = 0; i < 8; ++i) a[i] = bdw_s[c8 * 8 + i];
#pragma unroll
        for (int dy = 0; dy < 3; ++dy)
#pragma unroll
            for (int dx = 0; dx < 3; ++dx) {
                bf16x8 hv = ld8(&oh[((r + dy) * 10 + (cc + dx)) * 192 + c8 * 8]);
                const float* wp = &wdw_s[(dy * 3 + dx) * 192 + c8 * 8];
#pragma unroll
                for (int i = 0; i < 8; ++i)
                    a[i] += bf2f((unsigned short)hv[i]) * wp[i];
            }
        bf16x8 rv;
#pragma unroll
        for (int i = 0; i < 8; ++i) rv[i] = (short)f2bf(a[i]);
        *(bf16x8*)&cb[t * 200 + c8 * 8] = rv;
    }
    __syncthreads();

    f32x4 po[3][4];
#pragma unroll
    for (int n = 0; n < 3; ++n)
#pragma unroll
        for (int mt = 0; mt < 4; ++mt) po[n][mt] = (f32x4){0.f, 0.f, 0.f, 0.f};

    for (int kt = 0; kt < 6; ++kt) {
        bf16x8 af[4];
#pragma unroll
        for (int mt = 0; mt < 4; ++mt) af[mt] = ld8(cb + (mt * 16 + l16) * 200 + kt * 32 + quad * 8);
#pragma unroll
        for (int ntl = 0; ntl < 3; ++ntl) {
            bf16x8 bw = ld8(wp_m + (((kt * 12 + wave * 3 + ntl) * 64 + lane) << 3));
#pragma unroll
            for (int mt = 0; mt < 4; ++mt)
                po[ntl][mt] = __builtin_amdgcn_mfma_f32_16x16x32_bf16(af[mt], bw, po[ntl][mt], 0, 0, 0);
        }
    }

#pragma unroll
    for (int ntl = 0; ntl < 3; ++ntl) {
        int col = (wave * 3 + ntl) * 16 + l16;
        float bias = b_proj[col];
#pragma unroll
        for (int mt = 0; mt < 4; ++mt)
#pragma unroll
            for (int r = 0; r < 4; ++r) {
                int t = mt * 16 + quad * 4 + r;
                out[((img * 128 + y0 + (t >> 3)) * 128 + (x0 + (t & 7))) * 192 + col]
                    = po[ntl][mt][r] + bias;
            }
    }
}

// ---------------------------------------------------------------------------
extern "C" void kernel_launch(void* const* d_in, const int* in_sizes, int n_in,
                              void* d_out, int out_size, void* d_ws, size_t ws_size,
                              hipStream_t stream)
{
    const float* x      = (const float*)d_in[0];
    const float* w_qkv  = (const float*)d_in[1];
    const float* b_qkv  = (const float*)d_in[2];
    const float* w_dw   = (const float*)d_in[3];
    const float* b_dw   = (const float*)d_in[4];
    const float* w_proj = (const float*)d_in[5];
    const float* b_proj = (const float*)d_in[6];
    float* out = (float*)d_out;

    // ws (u16 units): wq_m 110592 | wp_m 36864 | o_scr 25165824
    unsigned short* wq_m  = (unsigned short*)d_ws;
    unsigned short* wp_m  = wq_m + 110592;
    unsigned short* o_scr = wq_m + 147456;

    repack_kernel<<<dim3(432), dim3(256), 0, stream>>>(w_qkv, w_proj, wq_m, wp_m);
    qkv_attn_fused<<<dim3(2048), dim3(384), 0, stream>>>(x, wq_m, b_qkv, o_scr);
    conv_proj_kernel<<<dim3(2048), dim3(256), 0, stream>>>(o_scr, w_dw, b_dw, wp_m, b_proj, out);
}

// Round 5
// 301.299 us; speedup vs baseline: 1.2678x; 1.0524x over previous
//
#include <hip/hip_runtime.h>

// Problem: B=8, H=W=128, C=192, NH=6, hd=32, window 8x8 (64 tok), 2048 windows.
// FP32 I/O; bf16 MFMA internally (threshold ~2% rel).
//
// Round 5: (a) fused QKV+attn reverted to the round-1 verbatim kernel (best
// measured: 125 us, passed; r2-r4 structural variants were neutral-to-broken).
// (b) conv_proj conv phase restructured: thread = (ch8-group, pixel row),
// weights held in registers per dy, halo row loaded+converted ONCE and slid
// across 8 output columns -> LDS b128/wave ~162 -> ~48 at equal FMA count.
// r4 lesson: one structural change per round; no bf16x4 LDS stores.

typedef __attribute__((ext_vector_type(8))) short bf16x8;
typedef __attribute__((ext_vector_type(4))) float f32x4;

__device__ __forceinline__ float bf2f(unsigned short h) {
    return __builtin_bit_cast(float, (unsigned int)h << 16);
}
__device__ __forceinline__ unsigned short f2bf(float f) {
    unsigned int u = __builtin_bit_cast(unsigned int, f);
    u += 0x7fffu + ((u >> 16) & 1u);
    return (unsigned short)(u >> 16);
}
__device__ __forceinline__ bf16x8 ld8(const unsigned short* p) {
    return *(const bf16x8*)p;
}
__device__ __forceinline__ bf16x8 ldf8(const float* p) {
    float4 a = *(const float4*)p;
    float4 b = *(const float4*)(p + 4);
    bf16x8 r;
    r[0] = (short)f2bf(a.x); r[1] = (short)f2bf(a.y);
    r[2] = (short)f2bf(a.z); r[3] = (short)f2bf(a.w);
    r[4] = (short)f2bf(b.x); r[5] = (short)f2bf(b.y);
    r[6] = (short)f2bf(b.z); r[7] = (short)f2bf(b.w);
    return r;
}
// unpack bf16x8 -> 8 fp32 (2 VALU per pair: shl / and-mask)
__device__ __forceinline__ void bf8tof(bf16x8 v, float* f) {
    union { bf16x8 v8; unsigned int u[4]; } cv; cv.v8 = v;
#pragma unroll
    for (int p = 0; p < 4; ++p) {
        f[2 * p]     = __builtin_bit_cast(float, cv.u[p] << 16);
        f[2 * p + 1] = __builtin_bit_cast(float, cv.u[p] & 0xffff0000u);
    }
}

// ---------------------------------------------------------------------------
// K0: repack w_qkv/w_proj (fp32) into bf16 MFMA B-fragment order. (unchanged)
// ---------------------------------------------------------------------------
__global__ __launch_bounds__(256) void repack_kernel(
    const float* __restrict__ w_qkv, const float* __restrict__ w_proj,
    unsigned short* __restrict__ wq_m, unsigned short* __restrict__ wp_m)
{
    int f = blockIdx.x * 256 + threadIdx.x;
    if (f < 6 * 36 * 64 * 8) {
        int j = f & 7, lane = (f >> 3) & 63, rest = f >> 9;
        int nt = rest % 36, kt = rest / 36;
        wq_m[f] = f2bf(w_qkv[(kt * 32 + (lane >> 4) * 8 + j) * 576 + nt * 16 + (lane & 15)]);
    }
    if (f < 6 * 12 * 64 * 8) {
        int j = f & 7, lane = (f >> 3) & 63, rest = f >> 9;
        int nt = rest % 12, kt = rest / 12;
        wp_m[f] = f2bf(w_proj[(kt * 32 + (lane >> 4) * 8 + j) * 192 + nt * 16 + (lane & 15)]);
    }
}

// ---------------------------------------------------------------------------
// K_F: fused QKV + attention — ROUND-1 VERBATIM (best measured: 125 us).
// 1 window per block, 6 waves, wave h == head h.
// LDS map (u16), total 57344 u16 = 114688 B:
//   xs  [0, 12800)                x tile bf16, [tok 64][stride 200]
//   per wave h: base = 12800 + h*7424
//     qs  +0      [tok 64][stride 40]
//     ks  +2560   [tok 64][stride 40]
//     vT  +5120   [dim 32][stride 72]
//     Ps  +0      [row 64][stride 72]   aliases qs/ks (same-wave in-order DS)
// ---------------------------------------------------------------------------
__global__ __launch_bounds__(384) void qkv_attn_fused(
    const float* __restrict__ x, const unsigned short* __restrict__ wq_m,
    const float* __restrict__ b_qkv, unsigned short* __restrict__ o_scr)
{
    __shared__ unsigned short smem[12800 + 6 * 7424];

    const int tid = threadIdx.x, lane = tid & 63, h = tid >> 6;
    const int l16 = lane & 15, quad = lane >> 4;
    const int wi = blockIdx.x;
    const int img = wi >> 8, wrem = wi & 255;
    const int y0 = (wrem >> 4) * 8, x0 = (wrem & 15) * 8;

    // ---- phase 0: stage x tile fp32 -> bf16 LDS (once per block) ----
    {
        const int token = tid / 6, seg = tid % 6;   // 64 tokens x 6 segs of 32
        const float* sp = x + ((img * 128 + y0 + (token >> 3)) * 128
                               + (x0 + (token & 7))) * 192 + seg * 32;
        unsigned short* dp = smem + token * 200 + seg * 32;
#pragma unroll
        for (int i = 0; i < 4; ++i)
            *(bf16x8*)(dp + i * 8) = ldf8(sp + i * 8);
    }
    __syncthreads();   // the only barrier in this kernel

    unsigned short* qs = smem + 12800 + h * 7424;
    unsigned short* ks = qs + 2560;
    unsigned short* vT = qs + 5120;
    unsigned short* Ps = qs;   // aliases qs/ks (see header comment)

    // ---- phase 1: QKV GEMM, the 6 N-tiles this head needs ----
    const int ntb[6] = {2 * h, 2 * h + 1, 12 + 2 * h, 13 + 2 * h, 24 + 2 * h, 25 + 2 * h};

    f32x4 acc[6][4];
#pragma unroll
    for (int s = 0; s < 6; ++s)
#pragma unroll
        for (int mt = 0; mt < 4; ++mt) acc[s][mt] = (f32x4){0.f, 0.f, 0.f, 0.f};

    for (int kt = 0; kt < 6; ++kt) {
        bf16x8 af[4];
#pragma unroll
        for (int mt = 0; mt < 4; ++mt)
            af[mt] = ld8(smem + (mt * 16 + l16) * 200 + kt * 32 + quad * 8);
#pragma unroll
        for (int s = 0; s < 6; ++s) {
            bf16x8 bw = ld8(wq_m + (((kt * 36 + ntb[s]) * 64 + lane) << 3));
#pragma unroll
            for (int mt = 0; mt < 4; ++mt)
                acc[s][mt] = __builtin_amdgcn_mfma_f32_16x16x32_bf16(af[mt], bw, acc[s][mt], 0, 0, 0);
        }
    }

    // ---- phase 2: scatter q (scaled), k, vT into this wave's LDS ----
#pragma unroll
    for (int s = 0; s < 6; ++s) {
        const float bias = b_qkv[ntb[s] * 16 + l16];
        if (s < 2) {
#pragma unroll
            for (int mt = 0; mt < 4; ++mt)
#pragma unroll
                for (int r = 0; r < 4; ++r)
                    qs[(mt * 16 + quad * 4 + r) * 40 + s * 16 + l16] =
                        f2bf((acc[s][mt][r] + bias) * 0.17677669529663687f);
        } else if (s < 4) {
#pragma unroll
            for (int mt = 0; mt < 4; ++mt)
#pragma unroll
                for (int r = 0; r < 4; ++r)
                    ks[(mt * 16 + quad * 4 + r) * 40 + (s - 2) * 16 + l16] =
                        f2bf(acc[s][mt][r] + bias);
        } else {
#pragma unroll
            for (int mt = 0; mt < 4; ++mt)
#pragma unroll
                for (int r = 0; r < 4; ++r)
                    vT[((s - 4) * 16 + l16) * 72 + mt * 16 + quad * 4 + r] =
                        f2bf(acc[s][mt][r] + bias);
        }
    }

    // ---- phase 3: S = q k^T (no barrier: same-wave LDS round-trip) ----
    bf16x8 aq[4], bk[4];
#pragma unroll
    for (int mt = 0; mt < 4; ++mt) aq[mt] = ld8(qs + (mt * 16 + l16) * 40 + quad * 8);
#pragma unroll
    for (int nt = 0; nt < 4; ++nt) bk[nt] = ld8(ks + (nt * 16 + l16) * 40 + quad * 8);

    f32x4 s4[4][4];
#pragma unroll
    for (int mt = 0; mt < 4; ++mt)
#pragma unroll
        for (int nt = 0; nt < 4; ++nt) {
            s4[mt][nt] = (f32x4){0.f, 0.f, 0.f, 0.f};
            s4[mt][nt] = __builtin_amdgcn_mfma_f32_16x16x32_bf16(aq[mt], bk[nt], s4[mt][nt], 0, 0, 0);
        }

    // ---- phase 4: softmax per row, write normalized P (aliases dead q/k) ----
#pragma unroll
    for (int mt = 0; mt < 4; ++mt) {
#pragma unroll
        for (int r = 0; r < 4; ++r) {
            float m = fmaxf(fmaxf(s4[mt][0][r], s4[mt][1][r]), fmaxf(s4[mt][2][r], s4[mt][3][r]));
            m = fmaxf(m, __shfl_xor(m, 1, 64));
            m = fmaxf(m, __shfl_xor(m, 2, 64));
            m = fmaxf(m, __shfl_xor(m, 4, 64));
            m = fmaxf(m, __shfl_xor(m, 8, 64));
            float pv[4], sum = 0.f;
#pragma unroll
            for (int nt = 0; nt < 4; ++nt) { pv[nt] = __expf(s4[mt][nt][r] - m); sum += pv[nt]; }
            sum += __shfl_xor(sum, 1, 64);
            sum += __shfl_xor(sum, 2, 64);
            sum += __shfl_xor(sum, 4, 64);
            sum += __shfl_xor(sum, 8, 64);
            const float inv = 1.f / sum;
            const int row = mt * 16 + quad * 4 + r;
#pragma unroll
            for (int nt = 0; nt < 4; ++nt)
                Ps[row * 72 + nt * 16 + l16] = f2bf(pv[nt] * inv);
        }
    }

    // ---- phase 5: O = P V ----
    f32x4 o[4][2];
#pragma unroll
    for (int mt = 0; mt < 4; ++mt)
#pragma unroll
        for (int n2 = 0; n2 < 2; ++n2) o[mt][n2] = (f32x4){0.f, 0.f, 0.f, 0.f};

#pragma unroll
    for (int kt2 = 0; kt2 < 2; ++kt2) {
        bf16x8 bv[2];
#pragma unroll
        for (int n2 = 0; n2 < 2; ++n2)
            bv[n2] = ld8(vT + (n2 * 16 + l16) * 72 + kt2 * 32 + quad * 8);
#pragma unroll
        for (int mt = 0; mt < 4; ++mt) {
            bf16x8 ap = ld8(Ps + (mt * 16 + l16) * 72 + kt2 * 32 + quad * 8);
#pragma unroll
            for (int n2 = 0; n2 < 2; ++n2)
                o[mt][n2] = __builtin_amdgcn_mfma_f32_16x16x32_bf16(ap, bv[n2], o[mt][n2], 0, 0, 0);
        }
    }

#pragma unroll
    for (int mt = 0; mt < 4; ++mt)
#pragma unroll
        for (int n2 = 0; n2 < 2; ++n2)
#pragma unroll
            for (int r = 0; r < 4; ++r) {
                const int token = mt * 16 + quad * 4 + r;
                o_scr[((img * 128 + y0 + (token >> 3)) * 128 + (x0 + (token & 7))) * 192
                      + h * 32 + n2 * 16 + l16] = f2bf(o[mt][n2][r]);
            }
}

// ---------------------------------------------------------------------------
// K_C: depthwise 3x3 + proj GEMM. Conv phase restructured for LDS-read reuse:
// 192 active threads = 24 ch8-groups x 8 pixel rows; each thread owns one
// (c8, row) and produces 8 tokens. Weights: 6 b128 LDS reads per dy (once);
// halo row: 10 b128 reads per dy, unpacked to fp32 once, slid across the 8
// output columns. LDS b128/thread: ~162 -> ~48 at equal FMA count.
// All loops fully unrolled -> static indexing (no scratch).
// ---------------------------------------------------------------------------
__global__ __launch_bounds__(256, 2) void conv_proj_kernel(
    const unsigned short* __restrict__ o_scr,
    const float* __restrict__ w_dw, const float* __restrict__ b_dw,
    const unsigned short* __restrict__ wp_m, const float* __restrict__ b_proj,
    float* __restrict__ out)
{
    __shared__ unsigned short oh[100 * 192];
    __shared__ unsigned short cb[64 * 200];
    __shared__ float wdw_s[9 * 192];
    __shared__ float bdw_s[192];

    const int tid = threadIdx.x, lane = tid & 63, wave = tid >> 6;
    const int l16 = lane & 15, quad = lane >> 4;
    const int img = blockIdx.x >> 8, wrem = blockIdx.x & 255;
    const int y0 = (wrem >> 4) * 8, x0 = (wrem & 15) * 8;

    for (int i = tid; i < 9 * 192; i += 256) wdw_s[i] = w_dw[i];
    if (tid < 192) bdw_s[tid] = b_dw[tid];

    for (int c = tid; c < 2400; c += 256) {
        int pix = c / 24, ck = c % 24;
        int py = y0 - 1 + pix / 10, px = x0 - 1 + pix % 10;
        uint4 v = {0u, 0u, 0u, 0u};
        if (py >= 0 && py < 128 && px >= 0 && px < 128)
            v = *(const uint4*)(o_scr + ((img * 128 + py) * 128 + px) * 192 + ck * 8);
        *(uint4*)(oh + pix * 192 + ck * 8) = v;
    }
    __syncthreads();

    // ---- conv phase: threads 0..191; thread = (grp = tid/24, c8 = tid%24) ----
    if (tid < 192) {
        const int c8 = tid % 24, grp = tid / 24;

        float acc8[8][8];                    // [out col j][channel i]
#pragma unroll
        for (int j = 0; j < 8; ++j)
#pragma unroll
            for (int i = 0; i < 8; ++i) acc8[j][i] = bdw_s[c8 * 8 + i];

#pragma unroll
        for (int dy = 0; dy < 3; ++dy) {
            float wt[3][8];                  // this dy's 3 taps (2 b128 each)
#pragma unroll
            for (int dx = 0; dx < 3; ++dx)
#pragma unroll
                for (int i = 0; i < 8; ++i)
                    wt[dx][i] = wdw_s[(dy * 3 + dx) * 192 + c8 * 8 + i];

            float rowf[10][8];               // halo row, unpacked once
#pragma unroll
            for (int cx = 0; cx < 10; ++cx)
                bf8tof(ld8(&oh[((grp + dy) * 10 + cx) * 192 + c8 * 8]), rowf[cx]);

#pragma unroll
            for (int j = 0; j < 8; ++j)
#pragma unroll
                for (int dx = 0; dx < 3; ++dx)
#pragma unroll
                    for (int i = 0; i < 8; ++i)
                        acc8[j][i] += rowf[j + dx][i] * wt[dx][i];
        }

#pragma unroll
        for (int j = 0; j < 8; ++j) {
            bf16x8 rv;
#pragma unroll
            for (int i = 0; i < 8; ++i) rv[i] = (short)f2bf(acc8[j][i]);
            *(bf16x8*)&cb[(grp * 8 + j) * 200 + c8 * 8] = rv;
        }
    }
    __syncthreads();

    // ---- proj GEMM (unchanged) ----
    f32x4 po[3][4];
#pragma unroll
    for (int n = 0; n < 3; ++n)
#pragma unroll
        for (int mt = 0; mt < 4; ++mt) po[n][mt] = (f32x4){0.f, 0.f, 0.f, 0.f};

    for (int kt = 0; kt < 6; ++kt) {
        bf16x8 af[4];
#pragma unroll
        for (int mt = 0; mt < 4; ++mt) af[mt] = ld8(cb + (mt * 16 + l16) * 200 + kt * 32 + quad * 8);
#pragma unroll
        for (int ntl = 0; ntl < 3; ++ntl) {
            bf16x8 bw = ld8(wp_m + (((kt * 12 + wave * 3 + ntl) * 64 + lane) << 3));
#pragma unroll
            for (int mt = 0; mt < 4; ++mt)
                po[ntl][mt] = __builtin_amdgcn_mfma_f32_16x16x32_bf16(af[mt], bw, po[ntl][mt], 0, 0, 0);
        }
    }

#pragma unroll
    for (int ntl = 0; ntl < 3; ++ntl) {
        int col = (wave * 3 + ntl) * 16 + l16;
        float bias = b_proj[col];
#pragma unroll
        for (int mt = 0; mt < 4; ++mt)
#pragma unroll
            for (int r = 0; r < 4; ++r) {
                int t = mt * 16 + quad * 4 + r;
                out[((img * 128 + y0 + (t >> 3)) * 128 + (x0 + (t & 7))) * 192 + col]
                    = po[ntl][mt][r] + bias;
            }
    }
}

// ---------------------------------------------------------------------------
extern "C" void kernel_launch(void* const* d_in, const int* in_sizes, int n_in,
                              void* d_out, int out_size, void* d_ws, size_t ws_size,
                              hipStream_t stream)
{
    const float* x      = (const float*)d_in[0];
    const float* w_qkv  = (const float*)d_in[1];
    const float* b_qkv  = (const float*)d_in[2];
    const float* w_dw   = (const float*)d_in[3];
    const float* b_dw   = (const float*)d_in[4];
    const float* w_proj = (const float*)d_in[5];
    const float* b_proj = (const float*)d_in[6];
    float* out = (float*)d_out;

    // ws (u16 units): wq_m 110592 | wp_m 36864 | o_scr 25165824
    unsigned short* wq_m  = (unsigned short*)d_ws;
    unsigned short* wp_m  = wq_m + 110592;
    unsigned short* o_scr = wq_m + 147456;

    repack_kernel<<<dim3(432), dim3(256), 0, stream>>>(w_qkv, w_proj, wq_m, wp_m);
    qkv_attn_fused<<<dim3(2048), dim3(384), 0, stream>>>(x, wq_m, b_qkv, o_scr);
    conv_proj_kernel<<<dim3(2048), dim3(256), 0, stream>>>(o_scr, w_dw, b_dw, wp_m, b_proj, out);
}